// Round 2
// baseline (754.406 us; speedup 1.0000x reference)
//
#include <hip/hip_runtime.h>
#include <hip/hip_bf16.h>

#define CCH 512
#define TTT 1024
#define BBB 8
#define NGRP 32
#define CPG 16
#define NHEAD 8
#define CHD 64
#define O_QKV 1536

__device__ __forceinline__ float us2f(unsigned short u) {
  union { unsigned int i; float f; } p; p.i = ((unsigned int)u) << 16; return p.f;
}
__device__ __forceinline__ unsigned short f2us(float f) {
  __hip_bfloat16 b = __float2bfloat16(f);
  return *reinterpret_cast<unsigned short*>(&b);
}

// ---------------- GroupNorm: one block per (b, group); f32 in -> bf16 out ----
__global__ __launch_bounds__(256) void gn_kernel(
    const float* __restrict__ x,
    const float* __restrict__ gw,
    const float* __restrict__ gb,
    unsigned short* __restrict__ h)
{
  const int bg = blockIdx.x;
  const int bb = bg >> 5, g = bg & 31;
  const size_t base = ((size_t)bb * CCH + (size_t)g * CPG) * TTT;
  const float4* xv = reinterpret_cast<const float4*>(x + base);
  ushort4* hv = reinterpret_cast<ushort4*>(h + base);
  const int tid = threadIdx.x;

  float s = 0.f, q = 0.f;
  for (int i = tid; i < 4096; i += 256) {
    float4 u = xv[i];
    s += (u.x + u.y) + (u.z + u.w);
    q += u.x * u.x + u.y * u.y + u.z * u.z + u.w * u.w;
  }
  #pragma unroll
  for (int off = 32; off > 0; off >>= 1) {
    s += __shfl_down(s, off);
    q += __shfl_down(q, off);
  }
  __shared__ float red[10];
  const int wid = tid >> 6, lane = tid & 63;
  if (lane == 0) { red[wid] = s; red[4 + wid] = q; }
  __syncthreads();
  if (tid == 0) {
    float S = red[0] + red[1] + red[2] + red[3];
    float Q = red[4] + red[5] + red[6] + red[7];
    float mu = S * (1.f / 16384.f);
    float var = Q * (1.f / 16384.f) - mu * mu;
    red[8] = mu;
    red[9] = rsqrtf(var + 1e-5f);
  }
  __syncthreads();
  const float mu = red[8], rstd = red[9];
  for (int i = tid; i < 4096; i += 256) {
    const int c = i >> 8;  // local channel (256 vec4 per channel row)
    const float wscale = gw[g * CPG + c] * rstd;
    const float wbias  = gb[g * CPG + c];
    float4 u = xv[i];
    ushort4 o;
    o.x = f2us(fmaf(u.x - mu, wscale, wbias));
    o.y = f2us(fmaf(u.y - mu, wscale, wbias));
    o.z = f2us(fmaf(u.z - mu, wscale, wbias));
    o.w = f2us(fmaf(u.w - mu, wscale, wbias));
    hv[i] = o;
  }
}

// ---------------- GEMM: out[b,o,t] = sum_c W[o,c]*H[b,c,t] + bias[o] (+resid) ----
// W f32, H bf16, out bf16 (OUT_F32=false) or f32 (+resid) (OUT_F32=true).
// 128x128 tile, BK=16, 256 threads, 8x8 per thread, f32 accumulate.
template<bool OUT_F32>
__global__ __launch_bounds__(256) void gemm_kernel(
    const float* __restrict__ Wm,             // (O, 512) f32
    const unsigned short* __restrict__ Hm,    // (B, 512, 1024) bf16
    const float* __restrict__ bias,           // (O) f32
    const float* __restrict__ resid,          // (B, O, 1024) f32 or nullptr
    void* __restrict__ outv,                  // (B, O, 1024)
    const int O)
{
  __shared__ __align__(16) float Ws[16][132];  // [k][o], padded
  __shared__ __align__(16) float Hs[16][132];  // [k][t], padded
  const int tid = threadIdx.x;
  const int bz = blockIdx.z;
  const int o0 = blockIdx.y * 128;
  const int t0 = blockIdx.x * 128;
  const unsigned short* Hb = Hm + (size_t)bz * CCH * TTT;
  const int tx = tid & 15, ty = tid >> 4;
  const int wrow = tid >> 1, wk0 = (tid & 1) * 8;
  const int hk = tid >> 4, ht0 = (tid & 15) * 8;

  float acc[8][8];
  #pragma unroll
  for (int i = 0; i < 8; i++)
    #pragma unroll
    for (int j = 0; j < 8; j++) acc[i][j] = 0.f;

  for (int kt = 0; kt < CCH; kt += 16) {
    const size_t waddr = (size_t)(o0 + wrow) * CCH + kt + wk0;
    float4 wa = *reinterpret_cast<const float4*>(&Wm[waddr]);
    float4 wb = *reinterpret_cast<const float4*>(&Wm[waddr + 4]);
    const size_t haddr = (size_t)(kt + hk) * TTT + t0 + ht0;
    ushort4 ha = *reinterpret_cast<const ushort4*>(&Hb[haddr]);
    ushort4 hb = *reinterpret_cast<const ushort4*>(&Hb[haddr + 4]);
    __syncthreads();
    Ws[wk0 + 0][wrow] = wa.x;
    Ws[wk0 + 1][wrow] = wa.y;
    Ws[wk0 + 2][wrow] = wa.z;
    Ws[wk0 + 3][wrow] = wa.w;
    Ws[wk0 + 4][wrow] = wb.x;
    Ws[wk0 + 5][wrow] = wb.y;
    Ws[wk0 + 6][wrow] = wb.z;
    Ws[wk0 + 7][wrow] = wb.w;
    float4 h0 = make_float4(us2f(ha.x), us2f(ha.y), us2f(ha.z), us2f(ha.w));
    float4 h1 = make_float4(us2f(hb.x), us2f(hb.y), us2f(hb.z), us2f(hb.w));
    *reinterpret_cast<float4*>(&Hs[hk][ht0])     = h0;
    *reinterpret_cast<float4*>(&Hs[hk][ht0 + 4]) = h1;
    __syncthreads();
    #pragma unroll
    for (int kk = 0; kk < 16; kk++) {
      float av[8], bv[8];
      #pragma unroll
      for (int i = 0; i < 8; i++) av[i] = Ws[kk][ty * 8 + i];
      #pragma unroll
      for (int j = 0; j < 8; j++) bv[j] = Hs[kk][tx * 8 + j];
      #pragma unroll
      for (int i = 0; i < 8; i++)
        #pragma unroll
        for (int j = 0; j < 8; j++)
          acc[i][j] = fmaf(av[i], bv[j], acc[i][j]);
    }
  }
  #pragma unroll
  for (int i = 0; i < 8; i++) {
    const int o = o0 + ty * 8 + i;
    const float bi = bias[o];
    const size_t obase = ((size_t)bz * O + o) * TTT + t0 + tx * 8;
    float v[8];
    #pragma unroll
    for (int j = 0; j < 8; j++) v[j] = acc[i][j] + bi;
    if (resid) {
      float4 r0 = *reinterpret_cast<const float4*>(&resid[obase]);
      float4 r1 = *reinterpret_cast<const float4*>(&resid[obase + 4]);
      v[0] += r0.x; v[1] += r0.y; v[2] += r0.z; v[3] += r0.w;
      v[4] += r1.x; v[5] += r1.y; v[6] += r1.z; v[7] += r1.w;
    }
    if (OUT_F32) {
      float* out = (float*)outv;
      *reinterpret_cast<float4*>(&out[obase])     = make_float4(v[0], v[1], v[2], v[3]);
      *reinterpret_cast<float4*>(&out[obase + 4]) = make_float4(v[4], v[5], v[6], v[7]);
    } else {
      unsigned short* out = (unsigned short*)outv;
      ushort4 s0, s1;
      s0.x = f2us(v[0]); s0.y = f2us(v[1]); s0.z = f2us(v[2]); s0.w = f2us(v[3]);
      s1.x = f2us(v[4]); s1.y = f2us(v[5]); s1.z = f2us(v[6]); s1.w = f2us(v[7]);
      *reinterpret_cast<ushort4*>(&out[obase])     = s0;
      *reinterpret_cast<ushort4*>(&out[obase + 4]) = s1;
    }
  }
}

// ---------------- Attention: one block per (bh, 64-query tile), flash-style ----
__global__ __launch_bounds__(256) void attn_kernel(
    const unsigned short* __restrict__ qkv,   // (B, 1536, 1024) bf16
    unsigned short* __restrict__ aout)        // (B, 512, 1024) bf16
{
  const int bh = blockIdx.y;
  const int b = bh >> 3, hh = bh & 7;
  const unsigned short* qp = qkv + ((size_t)b * O_QKV + (size_t)hh * (3 * CHD)) * TTT;
  const unsigned short* kp = qp + (size_t)CHD * TTT;
  const unsigned short* vp = kp + (size_t)CHD * TTT;
  const int t0 = blockIdx.x * 64;
  const int tid = threadIdx.x;
  const int iq = tid & 63;          // query owned by this thread
  const int quad = tid >> 6;        // 0..3
  const int jg = quad * 16;         // j-segment base == channel-segment base

  __shared__ __align__(16) float qs[64][65];   // [c][i]
  __shared__ __align__(16) float ks[64][65];   // [c][j]
  __shared__ __align__(16) float vst[64][65];  // [j][c]  (transposed)
  __shared__ __align__(16) float ss[64][65];   // [i][j]

  const float scale = 0.35355339059327373f;  // 64^-0.25

  // stage Q tile (scaled)
  for (int idx = tid; idx < 1024; idx += 256) {
    const int c = idx >> 4, tv = (idx & 15) * 4;
    ushort4 qu = *reinterpret_cast<const ushort4*>(&qp[(size_t)c * TTT + t0 + tv]);
    qs[c][tv + 0] = us2f(qu.x) * scale;
    qs[c][tv + 1] = us2f(qu.y) * scale;
    qs[c][tv + 2] = us2f(qu.z) * scale;
    qs[c][tv + 3] = us2f(qu.w) * scale;
  }

  float m = -1e30f, l = 0.f;
  float acc[16];
  #pragma unroll
  for (int cc = 0; cc < 16; cc++) acc[cc] = 0.f;

  for (int sb = 0; sb < TTT; sb += 64) {
    __syncthreads();  // prev iter reads done (also orders q-store on iter 0)
    for (int idx = tid; idx < 1024; idx += 256) {
      const int c = idx >> 4, jv = (idx & 15) * 4;
      ushort4 ku = *reinterpret_cast<const ushort4*>(&kp[(size_t)c * TTT + sb + jv]);
      ks[c][jv + 0] = us2f(ku.x) * scale;
      ks[c][jv + 1] = us2f(ku.y) * scale;
      ks[c][jv + 2] = us2f(ku.z) * scale;
      ks[c][jv + 3] = us2f(ku.w) * scale;
      ushort4 vu = *reinterpret_cast<const ushort4*>(&vp[(size_t)c * TTT + sb + jv]);
      vst[jv + 0][c] = us2f(vu.x);
      vst[jv + 1][c] = us2f(vu.y);
      vst[jv + 2][c] = us2f(vu.z);
      vst[jv + 3][c] = us2f(vu.w);
    }
    __syncthreads();
    // scores for (iq, jg..jg+15)
    float p[16];
    #pragma unroll
    for (int jj = 0; jj < 16; jj++) p[jj] = 0.f;
    for (int c = 0; c < 64; c++) {
      const float qc = qs[c][iq];
      #pragma unroll
      for (int jj = 0; jj < 16; jj++)
        p[jj] = fmaf(qc, ks[c][jg + jj], p[jj]);
    }
    #pragma unroll
    for (int jj = 0; jj < 16; jj++) ss[iq][jg + jj] = p[jj];
    __syncthreads();
    // full-row max (redundant x4 per query, identical results)
    float mx = -1e30f;
    for (int j = 0; j < 64; j++) mx = fmaxf(mx, ss[iq][j]);
    const float mnew = fmaxf(m, mx);
    const float sc = __expf(m - mnew);
    m = mnew;
    __syncthreads();  // all raw-score reads done before overwrite
    #pragma unroll
    for (int jj = 0; jj < 16; jj++) ss[iq][jg + jj] = __expf(p[jj] - mnew);
    __syncthreads();
    float rs = 0.f;
    for (int j = 0; j < 64; j++) rs += ss[iq][j];
    l = l * sc + rs;
    #pragma unroll
    for (int cc = 0; cc < 16; cc++) acc[cc] *= sc;
    for (int j = 0; j < 64; j++) {
      const float pj = ss[iq][j];
      #pragma unroll
      for (int cc = 0; cc < 16; cc++)
        acc[cc] = fmaf(pj, vst[j][jg + cc], acc[cc]);
    }
  }
  const float inv = 1.f / l;
  #pragma unroll
  for (int cc = 0; cc < 16; cc++) {
    const size_t off = ((size_t)b * CCH + (size_t)(hh * CHD + jg + cc)) * TTT + t0 + iq;
    aout[off] = f2us(acc[cc] * inv);
  }
}

extern "C" void kernel_launch(void* const* d_in, const int* in_sizes, int n_in,
                              void* d_out, int out_size, void* d_ws, size_t ws_size,
                              hipStream_t stream) {
  const float* x      = (const float*)d_in[0];
  const float* gn_w   = (const float*)d_in[1];
  const float* gn_b   = (const float*)d_in[2];
  const float* qkv_w  = (const float*)d_in[3];
  const float* qkv_b  = (const float*)d_in[4];
  const float* proj_w = (const float*)d_in[5];
  const float* proj_b = (const float*)d_in[6];
  float* out = (float*)d_out;

  // bf16 intermediates in workspace: 8 MB + 25.2 MB + 8 MB ≈ 41 MB
  unsigned short* h    = (unsigned short*)d_ws;
  unsigned short* qkvb = h + (size_t)BBB * CCH * TTT;
  unsigned short* av   = qkvb + (size_t)BBB * O_QKV * TTT;

  gn_kernel<<<dim3(BBB * NGRP), 256, 0, stream>>>(x, gn_w, gn_b, h);
  gemm_kernel<false><<<dim3(TTT / 128, O_QKV / 128, BBB), 256, 0, stream>>>(
      qkv_w, h, qkv_b, nullptr, (void*)qkvb, O_QKV);
  attn_kernel<<<dim3(TTT / 64, BBB * NHEAD), 256, 0, stream>>>(qkvb, av);
  gemm_kernel<true><<<dim3(TTT / 128, CCH / 128, BBB), 256, 0, stream>>>(
      proj_w, av, proj_b, x, (void*)out, CCH);
}

// Round 3
// 308.021 us; speedup vs baseline: 2.4492x; 2.4492x over previous
//
#include <hip/hip_runtime.h>
#include <hip/hip_bf16.h>

#define CCH 512
#define TTT 1024
#define BBB 8
#define NGRP 32
#define CPG 16
#define NHEAD 8
#define CHD 64
#define O_QKV 1536

typedef __attribute__((ext_vector_type(8))) short bf16x8;
typedef __attribute__((ext_vector_type(8))) unsigned short u16x8;
typedef __attribute__((ext_vector_type(4))) float f32x4;

__device__ __forceinline__ float us2f(unsigned short u) {
  union { unsigned int i; float f; } p; p.i = ((unsigned int)u) << 16; return p.f;
}
__device__ __forceinline__ unsigned short f2us(float f) {
  __hip_bfloat16 b = __float2bfloat16(f);
  return *reinterpret_cast<unsigned short*>(&b);
}

// ---------------- GroupNorm: one block per (b, group); f32 in -> bf16 out ----
__global__ __launch_bounds__(256) void gn_kernel(
    const float* __restrict__ x,
    const float* __restrict__ gw,
    const float* __restrict__ gb,
    unsigned short* __restrict__ h)
{
  const int bg = blockIdx.x;
  const int bb = bg >> 5, g = bg & 31;
  const size_t base = ((size_t)bb * CCH + (size_t)g * CPG) * TTT;
  const float4* xv = reinterpret_cast<const float4*>(x + base);
  ushort4* hv = reinterpret_cast<ushort4*>(h + base);
  const int tid = threadIdx.x;

  float s = 0.f, q = 0.f;
  for (int i = tid; i < 4096; i += 256) {
    float4 u = xv[i];
    s += (u.x + u.y) + (u.z + u.w);
    q += u.x * u.x + u.y * u.y + u.z * u.z + u.w * u.w;
  }
  #pragma unroll
  for (int off = 32; off > 0; off >>= 1) {
    s += __shfl_down(s, off);
    q += __shfl_down(q, off);
  }
  __shared__ float red[10];
  const int wid = tid >> 6, lane = tid & 63;
  if (lane == 0) { red[wid] = s; red[4 + wid] = q; }
  __syncthreads();
  if (tid == 0) {
    float S = red[0] + red[1] + red[2] + red[3];
    float Q = red[4] + red[5] + red[6] + red[7];
    float mu = S * (1.f / 16384.f);
    float var = Q * (1.f / 16384.f) - mu * mu;
    red[8] = mu;
    red[9] = rsqrtf(var + 1e-5f);
  }
  __syncthreads();
  const float mu = red[8], rstd = red[9];
  for (int i = tid; i < 4096; i += 256) {
    const int c = i >> 8;
    const float wscale = gw[g * CPG + c] * rstd;
    const float wbias  = gb[g * CPG + c];
    float4 u = xv[i];
    ushort4 o;
    o.x = f2us(fmaf(u.x - mu, wscale, wbias));
    o.y = f2us(fmaf(u.y - mu, wscale, wbias));
    o.z = f2us(fmaf(u.z - mu, wscale, wbias));
    o.w = f2us(fmaf(u.w - mu, wscale, wbias));
    hv[i] = o;
  }
}

// ---------------- GEMM (vector FMA, unchanged from R2) ----------------
template<bool OUT_F32>
__global__ __launch_bounds__(256) void gemm_kernel(
    const float* __restrict__ Wm,
    const unsigned short* __restrict__ Hm,
    const float* __restrict__ bias,
    const float* __restrict__ resid,
    void* __restrict__ outv,
    const int O)
{
  __shared__ __align__(16) float Ws[16][132];
  __shared__ __align__(16) float Hs[16][132];
  const int tid = threadIdx.x;
  const int bz = blockIdx.z;
  const int o0 = blockIdx.y * 128;
  const int t0 = blockIdx.x * 128;
  const unsigned short* Hb = Hm + (size_t)bz * CCH * TTT;
  const int tx = tid & 15, ty = tid >> 4;
  const int wrow = tid >> 1, wk0 = (tid & 1) * 8;
  const int hk = tid >> 4, ht0 = (tid & 15) * 8;

  float acc[8][8];
  #pragma unroll
  for (int i = 0; i < 8; i++)
    #pragma unroll
    for (int j = 0; j < 8; j++) acc[i][j] = 0.f;

  for (int kt = 0; kt < CCH; kt += 16) {
    const size_t waddr = (size_t)(o0 + wrow) * CCH + kt + wk0;
    float4 wa = *reinterpret_cast<const float4*>(&Wm[waddr]);
    float4 wb = *reinterpret_cast<const float4*>(&Wm[waddr + 4]);
    const size_t haddr = (size_t)(kt + hk) * TTT + t0 + ht0;
    ushort4 ha = *reinterpret_cast<const ushort4*>(&Hb[haddr]);
    ushort4 hb = *reinterpret_cast<const ushort4*>(&Hb[haddr + 4]);
    __syncthreads();
    Ws[wk0 + 0][wrow] = wa.x;
    Ws[wk0 + 1][wrow] = wa.y;
    Ws[wk0 + 2][wrow] = wa.z;
    Ws[wk0 + 3][wrow] = wa.w;
    Ws[wk0 + 4][wrow] = wb.x;
    Ws[wk0 + 5][wrow] = wb.y;
    Ws[wk0 + 6][wrow] = wb.z;
    Ws[wk0 + 7][wrow] = wb.w;
    float4 h0 = make_float4(us2f(ha.x), us2f(ha.y), us2f(ha.z), us2f(ha.w));
    float4 h1 = make_float4(us2f(hb.x), us2f(hb.y), us2f(hb.z), us2f(hb.w));
    *reinterpret_cast<float4*>(&Hs[hk][ht0])     = h0;
    *reinterpret_cast<float4*>(&Hs[hk][ht0 + 4]) = h1;
    __syncthreads();
    #pragma unroll
    for (int kk = 0; kk < 16; kk++) {
      float av[8], bv[8];
      #pragma unroll
      for (int i = 0; i < 8; i++) av[i] = Ws[kk][ty * 8 + i];
      #pragma unroll
      for (int j = 0; j < 8; j++) bv[j] = Hs[kk][tx * 8 + j];
      #pragma unroll
      for (int i = 0; i < 8; i++)
        #pragma unroll
        for (int j = 0; j < 8; j++)
          acc[i][j] = fmaf(av[i], bv[j], acc[i][j]);
    }
  }
  #pragma unroll
  for (int i = 0; i < 8; i++) {
    const int o = o0 + ty * 8 + i;
    const float bi = bias[o];
    const size_t obase = ((size_t)bz * O + o) * TTT + t0 + tx * 8;
    float v[8];
    #pragma unroll
    for (int j = 0; j < 8; j++) v[j] = acc[i][j] + bi;
    if (resid) {
      float4 r0 = *reinterpret_cast<const float4*>(&resid[obase]);
      float4 r1 = *reinterpret_cast<const float4*>(&resid[obase + 4]);
      v[0] += r0.x; v[1] += r0.y; v[2] += r0.z; v[3] += r0.w;
      v[4] += r1.x; v[5] += r1.y; v[6] += r1.z; v[7] += r1.w;
    }
    if (OUT_F32) {
      float* out = (float*)outv;
      *reinterpret_cast<float4*>(&out[obase])     = make_float4(v[0], v[1], v[2], v[3]);
      *reinterpret_cast<float4*>(&out[obase + 4]) = make_float4(v[4], v[5], v[6], v[7]);
    } else {
      unsigned short* out = (unsigned short*)outv;
      ushort4 s0, s1;
      s0.x = f2us(v[0]); s0.y = f2us(v[1]); s0.z = f2us(v[2]); s0.w = f2us(v[3]);
      s1.x = f2us(v[4]); s1.y = f2us(v[5]); s1.z = f2us(v[6]); s1.w = f2us(v[7]);
      *reinterpret_cast<ushort4*>(&out[obase])     = s0;
      *reinterpret_cast<ushort4*>(&out[obase + 4]) = s1;
    }
  }
}

// ---------------- MFMA flash attention ----------------
// Block: 4 waves, 64 queries (wave w owns q rows 16w..16w+15). KV tiles of 64.
// mfma_f32_16x16x32_bf16 layouts: A row=lane&15, k=(lane>>4)*8+i (contig);
// B col=lane&15, same k; C/D col=lane&15, row=(lane>>4)*4+reg.
__global__ __launch_bounds__(256) void attn_mfma(
    const unsigned short* __restrict__ qkv,   // (B, 1536, 1024) bf16
    unsigned short* __restrict__ aout)        // (B, 512, 1024) bf16
{
  const int bh = blockIdx.y;
  const int b = bh >> 3, hh = bh & 7;
  const unsigned short* qp = qkv + ((size_t)b * O_QKV + (size_t)hh * (3 * CHD)) * TTT;
  const unsigned short* kp = qp + (size_t)CHD * TTT;
  const unsigned short* vp = kp + (size_t)CHD * TTT;
  const int t0 = blockIdx.x * 64;
  const int tid = threadIdx.x;
  const int lane = tid & 63;
  const int w = tid >> 6;       // wave 0..3
  const int lg = lane >> 4;     // 0..3
  const int lr = lane & 15;     // 0..15

  // pad 72 keeps b128 reads 16B-aligned (72*2=144, 144%16==0)
  __shared__ __align__(16) unsigned short qT[64][72];  // [t][c]
  __shared__ __align__(16) unsigned short kT[64][72];  // [s][c]
  __shared__ __align__(16) unsigned short pS[64][72];  // [t][s]

  // ---- stage Q transposed (once) ----
  {
    const int c = tid >> 2, tf = (tid & 3) << 4;
    const unsigned short* src = qp + (size_t)c * TTT + t0 + tf;
    u16x8 a0 = *reinterpret_cast<const u16x8*>(src);
    u16x8 a1 = *reinterpret_cast<const u16x8*>(src + 8);
    #pragma unroll
    for (int j = 0; j < 8; j++) qT[tf + j][c] = a0[j];
    #pragma unroll
    for (int j = 0; j < 8; j++) qT[tf + 8 + j][c] = a1[j];
  }
  __syncthreads();

  // loop-invariant Q A-frags: A[t][c], t = 16w + lr
  const bf16x8 aq0 = *reinterpret_cast<const bf16x8*>(&qT[w * 16 + lr][lg * 8]);
  const bf16x8 aq1 = *reinterpret_cast<const bf16x8*>(&qT[w * 16 + lr][lg * 8 + 32]);

  f32x4 opv[4];
  #pragma unroll
  for (int cn = 0; cn < 4; cn++) opv[cn] = f32x4{0.f, 0.f, 0.f, 0.f};
  float mrow[4] = {-1e30f, -1e30f, -1e30f, -1e30f};
  float lrow[4] = {0.f, 0.f, 0.f, 0.f};  // per-lane partial (4 cols each)

  for (int sb = 0; sb < TTT; sb += 64) {
    __syncthreads();  // prev-iter kT/pS reads complete
    // ---- stage K tile transposed: kT[s][c] ----
    {
      const int c = tid >> 2, sf = (tid & 3) << 4;
      const unsigned short* src = kp + (size_t)c * TTT + sb + sf;
      u16x8 k0 = *reinterpret_cast<const u16x8*>(src);
      u16x8 k1 = *reinterpret_cast<const u16x8*>(src + 8);
      #pragma unroll
      for (int j = 0; j < 8; j++) kT[sf + j][c] = k0[j];
      #pragma unroll
      for (int j = 0; j < 8; j++) kT[sf + 8 + j][c] = k1[j];
    }
    __syncthreads();

    // ---- QK^T: W[t][s] strip 16x64 per wave ----
    f32x4 sc[4];
    #pragma unroll
    for (int sn = 0; sn < 4; sn++) {
      const bf16x8 bk0 = *reinterpret_cast<const bf16x8*>(&kT[sn * 16 + lr][lg * 8]);
      const bf16x8 bk1 = *reinterpret_cast<const bf16x8*>(&kT[sn * 16 + lr][lg * 8 + 32]);
      f32x4 t = __builtin_amdgcn_mfma_f32_16x16x32_bf16(aq0, bk0, f32x4{0.f, 0.f, 0.f, 0.f}, 0, 0, 0);
      sc[sn] = __builtin_amdgcn_mfma_f32_16x16x32_bf16(aq1, bk1, t, 0, 0, 0);
    }

    // ---- prefetch V B-frags from global (L2-hot); latency hides under softmax
    bf16x8 bv[4][2];
    #pragma unroll
    for (int cn = 0; cn < 4; cn++) {
      const unsigned short* vrow = vp + (size_t)(cn * 16 + lr) * TTT + sb + lg * 8;
      bv[cn][0] = *reinterpret_cast<const bf16x8*>(vrow);
      bv[cn][1] = *reinterpret_cast<const bf16x8*>(vrow + 32);
    }

    // ---- online softmax (rows r: t = 16w + 4lg + r; 16-lane group shares row)
    float pv[4][4];  // [sn][r]
    #pragma unroll
    for (int sn = 0; sn < 4; sn++)
      #pragma unroll
      for (int r = 0; r < 4; r++) pv[sn][r] = sc[sn][r] * 0.125f;

    float rescale[4];
    #pragma unroll
    for (int r = 0; r < 4; r++) {
      float mx = fmaxf(fmaxf(pv[0][r], pv[1][r]), fmaxf(pv[2][r], pv[3][r]));
      mx = fmaxf(mx, __shfl_xor(mx, 1));
      mx = fmaxf(mx, __shfl_xor(mx, 2));
      mx = fmaxf(mx, __shfl_xor(mx, 4));
      mx = fmaxf(mx, __shfl_xor(mx, 8));
      const float mn = fmaxf(mrow[r], mx);
      rescale[r] = __expf(mrow[r] - mn);
      mrow[r] = mn;
      float rs = 0.f;
      #pragma unroll
      for (int sn = 0; sn < 4; sn++) {
        pv[sn][r] = __expf(pv[sn][r] - mn);
        rs += pv[sn][r];
      }
      lrow[r] = lrow[r] * rescale[r] + rs;  // per-lane partial; reduced at end
    }
    #pragma unroll
    for (int cn = 0; cn < 4; cn++)
      #pragma unroll
      for (int r = 0; r < 4; r++) opv[cn][r] *= rescale[r];

    // ---- write P (C/D layout) to pS[t][s] as bf16 ----
    #pragma unroll
    for (int sn = 0; sn < 4; sn++)
      #pragma unroll
      for (int r = 0; r < 4; r++)
        pS[w * 16 + lg * 4 + r][sn * 16 + lr] = f2us(pv[sn][r]);
    __syncthreads();

    // ---- PV: D[t][c], A = P (pS), B = V (regs) ----
    const bf16x8 ap0 = *reinterpret_cast<const bf16x8*>(&pS[w * 16 + lr][lg * 8]);
    const bf16x8 ap1 = *reinterpret_cast<const bf16x8*>(&pS[w * 16 + lr][lg * 8 + 32]);
    #pragma unroll
    for (int cn = 0; cn < 4; cn++) {
      opv[cn] = __builtin_amdgcn_mfma_f32_16x16x32_bf16(ap0, bv[cn][0], opv[cn], 0, 0, 0);
      opv[cn] = __builtin_amdgcn_mfma_f32_16x16x32_bf16(ap1, bv[cn][1], opv[cn], 0, 0, 0);
    }
  }

  // ---- final l reduction + output ----
  float inv[4];
  #pragma unroll
  for (int r = 0; r < 4; r++) {
    float v = lrow[r];
    v += __shfl_xor(v, 1);
    v += __shfl_xor(v, 2);
    v += __shfl_xor(v, 4);
    v += __shfl_xor(v, 8);
    inv[r] = 1.f / v;
  }
  #pragma unroll
  for (int cn = 0; cn < 4; cn++) {
    const size_t crow = (size_t)b * CCH + (size_t)(hh * CHD + cn * 16 + lr);
    ushort4 o;
    o.x = f2us(opv[cn][0] * inv[0]);
    o.y = f2us(opv[cn][1] * inv[1]);
    o.z = f2us(opv[cn][2] * inv[2]);
    o.w = f2us(opv[cn][3] * inv[3]);
    *reinterpret_cast<ushort4*>(&aout[crow * TTT + t0 + w * 16 + lg * 4]) = o;
  }
}

extern "C" void kernel_launch(void* const* d_in, const int* in_sizes, int n_in,
                              void* d_out, int out_size, void* d_ws, size_t ws_size,
                              hipStream_t stream) {
  const float* x      = (const float*)d_in[0];
  const float* gn_w   = (const float*)d_in[1];
  const float* gn_b   = (const float*)d_in[2];
  const float* qkv_w  = (const float*)d_in[3];
  const float* qkv_b  = (const float*)d_in[4];
  const float* proj_w = (const float*)d_in[5];
  const float* proj_b = (const float*)d_in[6];
  float* out = (float*)d_out;

  unsigned short* h    = (unsigned short*)d_ws;
  unsigned short* qkvb = h + (size_t)BBB * CCH * TTT;
  unsigned short* av   = qkvb + (size_t)BBB * O_QKV * TTT;

  gn_kernel<<<dim3(BBB * NGRP), 256, 0, stream>>>(x, gn_w, gn_b, h);
  gemm_kernel<false><<<dim3(TTT / 128, O_QKV / 128, BBB), 256, 0, stream>>>(
      qkv_w, h, qkv_b, nullptr, (void*)qkvb, O_QKV);
  attn_mfma<<<dim3(TTT / 64, BBB * NHEAD), 256, 0, stream>>>(qkvb, av);
  gemm_kernel<true><<<dim3(TTT / 128, CCH / 128, BBB), 256, 0, stream>>>(
      proj_w, av, proj_b, x, (void*)out, CCH);
}

// Round 4
// 161.305 us; speedup vs baseline: 4.6769x; 1.9096x over previous
//
#include <hip/hip_runtime.h>
#include <hip/hip_bf16.h>

#define CCH 512
#define TTT 1024
#define BBB 8
#define NGRP 32
#define CPG 16
#define NHEAD 8
#define CHD 64
#define O_QKV 1536

typedef __attribute__((ext_vector_type(8))) short bf16x8;
typedef __attribute__((ext_vector_type(8))) unsigned short u16x8;
typedef __attribute__((ext_vector_type(4))) float f32x4;

__device__ __forceinline__ float us2f(unsigned short u) {
  union { unsigned int i; float f; } p; p.i = ((unsigned int)u) << 16; return p.f;
}
__device__ __forceinline__ unsigned short f2us(float f) {
  __hip_bfloat16 b = __float2bfloat16(f);
  return *reinterpret_cast<unsigned short*>(&b);
}

// ---------------- GroupNorm: one block per (b, group); f32 in -> bf16 out ----
__global__ __launch_bounds__(256) void gn_kernel(
    const float* __restrict__ x,
    const float* __restrict__ gw,
    const float* __restrict__ gb,
    unsigned short* __restrict__ h)
{
  const int bg = blockIdx.x;
  const int bb = bg >> 5, g = bg & 31;
  const size_t base = ((size_t)bb * CCH + (size_t)g * CPG) * TTT;
  const float4* xv = reinterpret_cast<const float4*>(x + base);
  ushort4* hv = reinterpret_cast<ushort4*>(h + base);
  const int tid = threadIdx.x;

  float s = 0.f, q = 0.f;
  for (int i = tid; i < 4096; i += 256) {
    float4 u = xv[i];
    s += (u.x + u.y) + (u.z + u.w);
    q += u.x * u.x + u.y * u.y + u.z * u.z + u.w * u.w;
  }
  #pragma unroll
  for (int off = 32; off > 0; off >>= 1) {
    s += __shfl_down(s, off);
    q += __shfl_down(q, off);
  }
  __shared__ float red[10];
  const int wid = tid >> 6, lane = tid & 63;
  if (lane == 0) { red[wid] = s; red[4 + wid] = q; }
  __syncthreads();
  if (tid == 0) {
    float S = red[0] + red[1] + red[2] + red[3];
    float Q = red[4] + red[5] + red[6] + red[7];
    float mu = S * (1.f / 16384.f);
    float var = Q * (1.f / 16384.f) - mu * mu;
    red[8] = mu;
    red[9] = rsqrtf(var + 1e-5f);
  }
  __syncthreads();
  const float mu = red[8], rstd = red[9];
  for (int i = tid; i < 4096; i += 256) {
    const int c = i >> 8;
    const float wscale = gw[g * CPG + c] * rstd;
    const float wbias  = gb[g * CPG + c];
    float4 u = xv[i];
    ushort4 o;
    o.x = f2us(fmaf(u.x - mu, wscale, wbias));
    o.y = f2us(fmaf(u.y - mu, wscale, wbias));
    o.z = f2us(fmaf(u.z - mu, wscale, wbias));
    o.w = f2us(fmaf(u.w - mu, wscale, wbias));
    hv[i] = o;
  }
}

// ---------------- MFMA GEMM: out[b,o,t] = sum_c W[o,c]*H[b,c,t] + bias (+resid) ----
// 128x128 tile, BK=64, 4 waves (each 64x64 = 4x4 frags of 16x16x32 bf16).
// A = W staged natural wa[o][c]; B = H scalar-transposed into hb[t][c].
template<bool OUT_F32>
__global__ __launch_bounds__(256) void gemm_mfma(
    const float* __restrict__ Wm,             // (O, 512) f32
    const unsigned short* __restrict__ Hm,    // (B, 512, 1024) bf16
    const float* __restrict__ bias,           // (O) f32
    const float* __restrict__ resid,          // (B, O, 1024) f32 or nullptr
    void* __restrict__ outv,                  // (B, O, 1024)
    const int O)
{
  __shared__ __align__(16) unsigned short wa[128][72];  // [o][c], pad->144B rows
  __shared__ __align__(16) unsigned short hb[128][72];  // [t][c]
  const int tid = threadIdx.x;
  const int bz = blockIdx.z;
  const int o0 = blockIdx.y * 128;
  const int t0 = blockIdx.x * 128;
  const unsigned short* Hb = Hm + (size_t)bz * CCH * TTT;
  const int lane = tid & 63, w = tid >> 6;
  const int lg = lane >> 4, lr = lane & 15;
  const int wr = w >> 1, wc = w & 1;   // wave tile: o = wr*64, t = wc*64

  // staging indices
  const int srow = tid >> 1, scol = (tid & 1) * 32;   // W: 2 threads/row
  const int hc = tid >> 2, htf = (tid & 3) * 32;      // H: 4 threads/c-row

  f32x4 acc[4][4];
  #pragma unroll
  for (int m = 0; m < 4; m++)
    #pragma unroll
    for (int n = 0; n < 4; n++) acc[m][n] = f32x4{0.f, 0.f, 0.f, 0.f};

  for (int kt = 0; kt < CCH; kt += 64) {
    // load before barrier (hide latency under prev compute's tail)
    const float* wsrc = Wm + (size_t)(o0 + srow) * CCH + kt + scol;
    float4 wv[8];
    #pragma unroll
    for (int q = 0; q < 8; q++) wv[q] = reinterpret_cast<const float4*>(wsrc)[q];
    const unsigned short* hsrc = Hb + (size_t)(kt + hc) * TTT + t0 + htf;
    u16x8 hv[4];
    #pragma unroll
    for (int q = 0; q < 4; q++) hv[q] = reinterpret_cast<const u16x8*>(hsrc)[q];

    __syncthreads();  // previous iteration's frag reads complete
    #pragma unroll
    for (int q = 0; q < 4; q++) {
      u16x8 t;
      t[0] = f2us(wv[2 * q].x); t[1] = f2us(wv[2 * q].y);
      t[2] = f2us(wv[2 * q].z); t[3] = f2us(wv[2 * q].w);
      t[4] = f2us(wv[2 * q + 1].x); t[5] = f2us(wv[2 * q + 1].y);
      t[6] = f2us(wv[2 * q + 1].z); t[7] = f2us(wv[2 * q + 1].w);
      *reinterpret_cast<u16x8*>(&wa[srow][scol + q * 8]) = t;
    }
    #pragma unroll
    for (int q = 0; q < 4; q++)
      #pragma unroll
      for (int j = 0; j < 8; j++)
        hb[htf + q * 8 + j][hc] = hv[q][j];
    __syncthreads();

    #pragma unroll
    for (int k2 = 0; k2 < 2; k2++) {
      bf16x8 af[4];
      #pragma unroll
      for (int m = 0; m < 4; m++)
        af[m] = *reinterpret_cast<const bf16x8*>(&wa[wr * 64 + m * 16 + lr][k2 * 32 + lg * 8]);
      #pragma unroll
      for (int n = 0; n < 4; n++) {
        const bf16x8 bf_ = *reinterpret_cast<const bf16x8*>(&hb[wc * 64 + n * 16 + lr][k2 * 32 + lg * 8]);
        #pragma unroll
        for (int m = 0; m < 4; m++)
          acc[m][n] = __builtin_amdgcn_mfma_f32_16x16x32_bf16(af[m], bf_, acc[m][n], 0, 0, 0);
      }
    }
  }

  // epilogue: D col(lane&15)=t, row(lg*4+reg)=o
  #pragma unroll
  for (int m = 0; m < 4; m++) {
    #pragma unroll
    for (int r = 0; r < 4; r++) {
      const int o = o0 + wr * 64 + m * 16 + lg * 4 + r;
      const float bi = bias[o];
      const size_t rowbase = ((size_t)bz * O + o) * TTT + t0 + wc * 64 + lr;
      #pragma unroll
      for (int n = 0; n < 4; n++) {
        float v = acc[m][n][r] + bi;
        const size_t idx = rowbase + n * 16;
        if (OUT_F32) {
          if (resid) v += resid[idx];
          reinterpret_cast<float*>(outv)[idx] = v;
        } else {
          reinterpret_cast<unsigned short*>(outv)[idx] = f2us(v);
        }
      }
    }
  }
}

// ---------------- MFMA flash attention (unchanged from R3) ----------------
__global__ __launch_bounds__(256) void attn_mfma(
    const unsigned short* __restrict__ qkv,   // (B, 1536, 1024) bf16
    unsigned short* __restrict__ aout)        // (B, 512, 1024) bf16
{
  const int bh = blockIdx.y;
  const int b = bh >> 3, hh = bh & 7;
  const unsigned short* qp = qkv + ((size_t)b * O_QKV + (size_t)hh * (3 * CHD)) * TTT;
  const unsigned short* kp = qp + (size_t)CHD * TTT;
  const unsigned short* vp = kp + (size_t)CHD * TTT;
  const int t0 = blockIdx.x * 64;
  const int tid = threadIdx.x;
  const int lane = tid & 63;
  const int w = tid >> 6;
  const int lg = lane >> 4;
  const int lr = lane & 15;

  __shared__ __align__(16) unsigned short qT[64][72];
  __shared__ __align__(16) unsigned short kT[64][72];
  __shared__ __align__(16) unsigned short pS[64][72];

  {
    const int c = tid >> 2, tf = (tid & 3) << 4;
    const unsigned short* src = qp + (size_t)c * TTT + t0 + tf;
    u16x8 a0 = *reinterpret_cast<const u16x8*>(src);
    u16x8 a1 = *reinterpret_cast<const u16x8*>(src + 8);
    #pragma unroll
    for (int j = 0; j < 8; j++) qT[tf + j][c] = a0[j];
    #pragma unroll
    for (int j = 0; j < 8; j++) qT[tf + 8 + j][c] = a1[j];
  }
  __syncthreads();

  const bf16x8 aq0 = *reinterpret_cast<const bf16x8*>(&qT[w * 16 + lr][lg * 8]);
  const bf16x8 aq1 = *reinterpret_cast<const bf16x8*>(&qT[w * 16 + lr][lg * 8 + 32]);

  f32x4 opv[4];
  #pragma unroll
  for (int cn = 0; cn < 4; cn++) opv[cn] = f32x4{0.f, 0.f, 0.f, 0.f};
  float mrow[4] = {-1e30f, -1e30f, -1e30f, -1e30f};
  float lrow[4] = {0.f, 0.f, 0.f, 0.f};

  for (int sb = 0; sb < TTT; sb += 64) {
    __syncthreads();
    {
      const int c = tid >> 2, sf = (tid & 3) << 4;
      const unsigned short* src = kp + (size_t)c * TTT + sb + sf;
      u16x8 k0 = *reinterpret_cast<const u16x8*>(src);
      u16x8 k1 = *reinterpret_cast<const u16x8*>(src + 8);
      #pragma unroll
      for (int j = 0; j < 8; j++) kT[sf + j][c] = k0[j];
      #pragma unroll
      for (int j = 0; j < 8; j++) kT[sf + 8 + j][c] = k1[j];
    }
    __syncthreads();

    f32x4 sc[4];
    #pragma unroll
    for (int sn = 0; sn < 4; sn++) {
      const bf16x8 bk0 = *reinterpret_cast<const bf16x8*>(&kT[sn * 16 + lr][lg * 8]);
      const bf16x8 bk1 = *reinterpret_cast<const bf16x8*>(&kT[sn * 16 + lr][lg * 8 + 32]);
      f32x4 t = __builtin_amdgcn_mfma_f32_16x16x32_bf16(aq0, bk0, f32x4{0.f, 0.f, 0.f, 0.f}, 0, 0, 0);
      sc[sn] = __builtin_amdgcn_mfma_f32_16x16x32_bf16(aq1, bk1, t, 0, 0, 0);
    }

    bf16x8 bv[4][2];
    #pragma unroll
    for (int cn = 0; cn < 4; cn++) {
      const unsigned short* vrow = vp + (size_t)(cn * 16 + lr) * TTT + sb + lg * 8;
      bv[cn][0] = *reinterpret_cast<const bf16x8*>(vrow);
      bv[cn][1] = *reinterpret_cast<const bf16x8*>(vrow + 32);
    }

    float pv[4][4];
    #pragma unroll
    for (int sn = 0; sn < 4; sn++)
      #pragma unroll
      for (int r = 0; r < 4; r++) pv[sn][r] = sc[sn][r] * 0.125f;

    float rescale[4];
    #pragma unroll
    for (int r = 0; r < 4; r++) {
      float mx = fmaxf(fmaxf(pv[0][r], pv[1][r]), fmaxf(pv[2][r], pv[3][r]));
      mx = fmaxf(mx, __shfl_xor(mx, 1));
      mx = fmaxf(mx, __shfl_xor(mx, 2));
      mx = fmaxf(mx, __shfl_xor(mx, 4));
      mx = fmaxf(mx, __shfl_xor(mx, 8));
      const float mn = fmaxf(mrow[r], mx);
      rescale[r] = __expf(mrow[r] - mn);
      mrow[r] = mn;
      float rs = 0.f;
      #pragma unroll
      for (int sn = 0; sn < 4; sn++) {
        pv[sn][r] = __expf(pv[sn][r] - mn);
        rs += pv[sn][r];
      }
      lrow[r] = lrow[r] * rescale[r] + rs;
    }
    #pragma unroll
    for (int cn = 0; cn < 4; cn++)
      #pragma unroll
      for (int r = 0; r < 4; r++) opv[cn][r] *= rescale[r];

    #pragma unroll
    for (int sn = 0; sn < 4; sn++)
      #pragma unroll
      for (int r = 0; r < 4; r++)
        pS[w * 16 + lg * 4 + r][sn * 16 + lr] = f2us(pv[sn][r]);
    __syncthreads();

    const bf16x8 ap0 = *reinterpret_cast<const bf16x8*>(&pS[w * 16 + lr][lg * 8]);
    const bf16x8 ap1 = *reinterpret_cast<const bf16x8*>(&pS[w * 16 + lr][lg * 8 + 32]);
    #pragma unroll
    for (int cn = 0; cn < 4; cn++) {
      opv[cn] = __builtin_amdgcn_mfma_f32_16x16x32_bf16(ap0, bv[cn][0], opv[cn], 0, 0, 0);
      opv[cn] = __builtin_amdgcn_mfma_f32_16x16x32_bf16(ap1, bv[cn][1], opv[cn], 0, 0, 0);
    }
  }

  float inv[4];
  #pragma unroll
  for (int r = 0; r < 4; r++) {
    float v = lrow[r];
    v += __shfl_xor(v, 1);
    v += __shfl_xor(v, 2);
    v += __shfl_xor(v, 4);
    v += __shfl_xor(v, 8);
    inv[r] = 1.f / v;
  }
  #pragma unroll
  for (int cn = 0; cn < 4; cn++) {
    const size_t crow = (size_t)b * CCH + (size_t)(hh * CHD + cn * 16 + lr);
    ushort4 o;
    o.x = f2us(opv[cn][0] * inv[0]);
    o.y = f2us(opv[cn][1] * inv[1]);
    o.z = f2us(opv[cn][2] * inv[2]);
    o.w = f2us(opv[cn][3] * inv[3]);
    *reinterpret_cast<ushort4*>(&aout[crow * TTT + t0 + w * 16 + lg * 4]) = o;
  }
}

extern "C" void kernel_launch(void* const* d_in, const int* in_sizes, int n_in,
                              void* d_out, int out_size, void* d_ws, size_t ws_size,
                              hipStream_t stream) {
  const float* x      = (const float*)d_in[0];
  const float* gn_w   = (const float*)d_in[1];
  const float* gn_b   = (const float*)d_in[2];
  const float* qkv_w  = (const float*)d_in[3];
  const float* qkv_b  = (const float*)d_in[4];
  const float* proj_w = (const float*)d_in[5];
  const float* proj_b = (const float*)d_in[6];
  float* out = (float*)d_out;

  unsigned short* h    = (unsigned short*)d_ws;
  unsigned short* qkvb = h + (size_t)BBB * CCH * TTT;
  unsigned short* av   = qkvb + (size_t)BBB * O_QKV * TTT;

  gn_kernel<<<dim3(BBB * NGRP), 256, 0, stream>>>(x, gn_w, gn_b, h);
  gemm_mfma<false><<<dim3(TTT / 128, O_QKV / 128, BBB), 256, 0, stream>>>(
      qkv_w, h, qkv_b, nullptr, (void*)qkvb, O_QKV);
  attn_mfma<<<dim3(TTT / 64, BBB * NHEAD), 256, 0, stream>>>(qkvb, av);
  gemm_mfma<true><<<dim3(TTT / 128, CCH / 128, BBB), 256, 0, stream>>>(
      proj_w, av, proj_b, x, (void*)out, CCH);
}